// Round 1
// baseline (7008.546 us; speedup 1.0000x reference)
//
#include <hip/hip_runtime.h>
#include <math.h>

#define BATCH   65536
#define DIM     64
#define HID     128
#define SPLIT   32
#define NBINS   8
#define PDIM    25          // 3*NBINS+1
#define NLAYERS 6
#define R_MIN   (-5.0f)
#define R_MAX   (5.0f)
#define MIN_BIN   1.0e-4f
#define MIN_SLOPE 1.0e-4f
#define SOFF      0.54116666f   // log(exp(1-MIN_SLOPE)-1), computed in f64

#define ROWS 32
#define NT   256

// One coupling layer, fused MLP + RQS spline.
// Each block owns ROWS batch rows completely: it reads all of xin for those
// rows before writing any of yout, so xin == yout (in-place) is safe for
// layers >= 1. Layer 0 reads d_in's x and writes d_out's y region.
__global__ __launch_bounds__(NT) void flow_layer(
    const float* xin, float* yout, float* logdet, const int first,
    const float* __restrict__ W1, const float* __restrict__ b1,
    const float* __restrict__ W2, const float* __restrict__ b2,
    const float* __restrict__ W3, const float* __restrict__ b3,
    const float* __restrict__ W4, const float* __restrict__ b4,
    const int* __restrict__ mi, const int* __restrict__ ti)
{
    __shared__ float xm_s[ROWS][SPLIT + 1];   // gathered masked half (copied through)
    __shared__ float xt_s[ROWS][SPLIT + 1];   // gathered transformed half
    __shared__ float hA[ROWS][HID + 1];       // h1, then h3
    __shared__ float hB[ROWS][HID + 1];       // h2
    __shared__ float ldp[8][ROWS + 1];        // per-group logdet partials
    __shared__ int   mi_s[SPLIT];
    __shared__ int   ti_s[SPLIT];

    const int tid   = threadIdx.x;
    const int rbase = blockIdx.x * ROWS;

    if (tid < SPLIT) { mi_s[tid] = mi[tid]; ti_s[tid] = ti[tid]; }
    for (int idx = tid; idx < ROWS * SPLIT; idx += NT) {
        const int r = idx >> 5, k = idx & 31;
        const float* row = xin + (size_t)(rbase + r) * DIM;
        xm_s[r][k] = row[mi[k]];
        xt_s[r][k] = row[ti[k]];
    }
    __syncthreads();

    const int r = tid & 31;   // lane = row -> conflict-free LDS (stride HID+1)
    const int g = tid >> 5;   // 0..7: output-neuron group
    float acc[16];

    // ---- h1 = relu(xm @ W1^T + b1)   [K = 32] ----
    {
        const float* W = W1 + (size_t)(g * 16) * SPLIT;
        #pragma unroll
        for (int jj = 0; jj < 16; ++jj) acc[jj] = b1[g * 16 + jj];
        for (int k = 0; k < SPLIT; ++k) {
            const float xv = xm_s[r][k];
            #pragma unroll
            for (int jj = 0; jj < 16; ++jj)
                acc[jj] = fmaf(W[jj * SPLIT + k], xv, acc[jj]);
        }
        #pragma unroll
        for (int jj = 0; jj < 16; ++jj) hA[r][g * 16 + jj] = fmaxf(acc[jj], 0.0f);
    }
    __syncthreads();

    // ---- h2 = relu(h1 @ W2^T + b2)   [K = 128, float4 weight loads] ----
    {
        const float* W = W2 + (size_t)(g * 16) * HID;
        #pragma unroll
        for (int jj = 0; jj < 16; ++jj) acc[jj] = b2[g * 16 + jj];
        for (int k4 = 0; k4 < HID / 4; ++k4) {
            const float h0 = hA[r][k4 * 4 + 0];
            const float h1 = hA[r][k4 * 4 + 1];
            const float h2 = hA[r][k4 * 4 + 2];
            const float h3 = hA[r][k4 * 4 + 3];
            #pragma unroll
            for (int jj = 0; jj < 16; ++jj) {
                const float4 w = *reinterpret_cast<const float4*>(&W[jj * HID + k4 * 4]);
                acc[jj] = fmaf(w.x, h0, acc[jj]);
                acc[jj] = fmaf(w.y, h1, acc[jj]);
                acc[jj] = fmaf(w.z, h2, acc[jj]);
                acc[jj] = fmaf(w.w, h3, acc[jj]);
            }
        }
        #pragma unroll
        for (int jj = 0; jj < 16; ++jj) hB[r][g * 16 + jj] = fmaxf(acc[jj], 0.0f);
    }
    __syncthreads();

    // ---- h3 = relu(h2 @ W3^T + b3)   [K = 128] ----
    {
        const float* W = W3 + (size_t)(g * 16) * HID;
        #pragma unroll
        for (int jj = 0; jj < 16; ++jj) acc[jj] = b3[g * 16 + jj];
        for (int k4 = 0; k4 < HID / 4; ++k4) {
            const float h0 = hB[r][k4 * 4 + 0];
            const float h1 = hB[r][k4 * 4 + 1];
            const float h2 = hB[r][k4 * 4 + 2];
            const float h3 = hB[r][k4 * 4 + 3];
            #pragma unroll
            for (int jj = 0; jj < 16; ++jj) {
                const float4 w = *reinterpret_cast<const float4*>(&W[jj * HID + k4 * 4]);
                acc[jj] = fmaf(w.x, h0, acc[jj]);
                acc[jj] = fmaf(w.y, h1, acc[jj]);
                acc[jj] = fmaf(w.z, h2, acc[jj]);
                acc[jj] = fmaf(w.w, h3, acc[jj]);
            }
        }
        #pragma unroll
        for (int jj = 0; jj < 16; ++jj) hA[r][g * 16 + jj] = fmaxf(acc[jj], 0.0f);
    }
    __syncthreads();

    // ---- params (25 per t-dim) + RQS spline, fused; t = g + tt*8 ----
    float ldacc = 0.0f;
    #pragma unroll 1
    for (int tt = 0; tt < 4; ++tt) {
        const int t = g + tt * 8;
        float p[PDIM];
        {
            const float* W  = W4 + (size_t)(t * PDIM) * HID;
            const float* bb = b4 + t * PDIM;
            #pragma unroll
            for (int j = 0; j < PDIM; ++j) p[j] = bb[j];
            for (int k4 = 0; k4 < HID / 4; ++k4) {
                const float h0 = hA[r][k4 * 4 + 0];
                const float h1 = hA[r][k4 * 4 + 1];
                const float h2 = hA[r][k4 * 4 + 2];
                const float h3 = hA[r][k4 * 4 + 3];
                #pragma unroll
                for (int j = 0; j < PDIM; ++j) {
                    const float4 w = *reinterpret_cast<const float4*>(&W[j * HID + k4 * 4]);
                    p[j] = fmaf(w.x, h0, p[j]);
                    p[j] = fmaf(w.y, h1, p[j]);
                    p[j] = fmaf(w.z, h2, p[j]);
                    p[j] = fmaf(w.w, h3, p[j]);
                }
            }
        }

        // softmax -> widths
        float wd[NBINS], hg[NBINS], sl[NBINS + 1];
        {
            float mx = p[0];
            #pragma unroll
            for (int i = 1; i < NBINS; ++i) mx = fmaxf(mx, p[i]);
            float sum = 0.0f;
            #pragma unroll
            for (int i = 0; i < NBINS; ++i) { wd[i] = __expf(p[i] - mx); sum += wd[i]; }
            const float sc = ((R_MAX - R_MIN) - NBINS * MIN_BIN) / sum;
            #pragma unroll
            for (int i = 0; i < NBINS; ++i) wd[i] = wd[i] * sc + MIN_BIN;
        }
        // softmax -> heights
        {
            float mx = p[NBINS];
            #pragma unroll
            for (int i = 1; i < NBINS; ++i) mx = fmaxf(mx, p[NBINS + i]);
            float sum = 0.0f;
            #pragma unroll
            for (int i = 0; i < NBINS; ++i) { hg[i] = __expf(p[NBINS + i] - mx); sum += hg[i]; }
            const float sc = ((R_MAX - R_MIN) - NBINS * MIN_BIN) / sum;
            #pragma unroll
            for (int i = 0; i < NBINS; ++i) hg[i] = hg[i] * sc + MIN_BIN;
        }
        // softplus -> slopes (K+1 of them)
        #pragma unroll
        for (int i = 0; i < NBINS + 1; ++i) {
            const float z  = p[2 * NBINS + i] + SOFF;
            const float sp = (z > 15.0f) ? z : log1pf(__expf(z));
            sl[i] = sp + MIN_SLOPE;
        }
        // knot positions (cumsum); all arrays static-indexed via full unroll
        float xp[NBINS + 1], yp[NBINS + 1];
        xp[0] = R_MIN; yp[0] = R_MIN;
        #pragma unroll
        for (int i = 0; i < NBINS; ++i) { xp[i + 1] = xp[i] + wd[i]; yp[i + 1] = yp[i] + hg[i]; }

        const float x = xt_s[r][t];
        int b = 0;
        #pragma unroll
        for (int i = 1; i < NBINS; ++i) b += (xp[i] <= x) ? 1 : 0;

        float x_k = xp[0], x_k1 = xp[1], y_k = yp[0], y_k1 = yp[1], d_k = sl[0], d_k1 = sl[1];
        #pragma unroll
        for (int i = 1; i < NBINS; ++i) {
            if (b == i) { x_k = xp[i]; x_k1 = xp[i + 1]; y_k = yp[i]; y_k1 = yp[i + 1];
                          d_k = sl[i]; d_k1 = sl[i + 1]; }
        }

        const float w    = x_k1 - x_k;
        const float h    = y_k1 - y_k;
        float xi = (x - x_k) / w;
        xi = fminf(fmaxf(xi, 0.0f), 1.0f);
        const float s    = h / w;
        const float xi1m = 1.0f - xi;
        const float q    = xi * xi1m;
        const float num  = s * xi * xi + d_k * q;
        const float den  = s + (d_k1 + d_k - 2.0f * s) * q;
        const float y_sp = y_k + h * num / den;
        const float deriv = s * s * (d_k1 * xi * xi + 2.0f * s * q + d_k * xi1m * xi1m) / (den * den);

        const bool below = x < R_MIN;
        const bool above = x > R_MAX;
        const float yv = below ? ((x - R_MIN) * sl[0]     + R_MIN)
                       : (above ? ((x - R_MAX) * sl[NBINS] + R_MAX) : y_sp);
        const float dv = below ? sl[0] : (above ? sl[NBINS] : deriv);
        ldacc += __logf(dv);

        yout[(size_t)(rbase + r) * DIM + ti_s[t]] = yv;
    }

    ldp[g][r] = ldacc;
    __syncthreads();

    // copy-through of the masked half
    for (int idx = tid; idx < ROWS * SPLIT; idx += NT) {
        const int rr = idx >> 5, k = idx & 31;
        yout[(size_t)(rbase + rr) * DIM + mi_s[k]] = xm_s[rr][k];
    }
    // deterministic per-row logdet reduction (fixed order over 8 groups)
    if (tid < ROWS) {
        float sum = 0.0f;
        #pragma unroll
        for (int gg = 0; gg < 8; ++gg) sum += ldp[gg][tid];
        const int row = rbase + tid;
        if (first) logdet[row] = sum;
        else       logdet[row] += sum;
    }
}

extern "C" void kernel_launch(void* const* d_in, const int* in_sizes, int n_in,
                              void* d_out, int out_size, void* d_ws, size_t ws_size,
                              hipStream_t stream) {
    const float* x  = (const float*)d_in[0];
    const float* W1 = (const float*)d_in[1];
    const float* b1 = (const float*)d_in[2];
    const float* W2 = (const float*)d_in[3];
    const float* b2 = (const float*)d_in[4];
    const float* W3 = (const float*)d_in[5];
    const float* b3 = (const float*)d_in[6];
    const float* W4 = (const float*)d_in[7];
    const float* b4 = (const float*)d_in[8];
    const int*   mi = (const int*)d_in[9];
    const int*   ti = (const int*)d_in[10];

    float* y      = (float*)d_out;
    float* logdet = y + (size_t)BATCH * DIM;

    dim3 grid(BATCH / ROWS), block(NT);
    for (int L = 0; L < NLAYERS; ++L) {
        flow_layer<<<grid, block, 0, stream>>>(
            (L == 0) ? x : y, y, logdet, (L == 0) ? 1 : 0,
            W1 + (size_t)L * HID * SPLIT,       b1 + L * HID,
            W2 + (size_t)L * HID * HID,         b2 + L * HID,
            W3 + (size_t)L * HID * HID,         b3 + L * HID,
            W4 + (size_t)L * SPLIT * PDIM * HID, b4 + L * SPLIT * PDIM,
            mi + L * SPLIT, ti + L * SPLIT);
    }
}

// Round 2
// 1062.394 us; speedup vs baseline: 6.5969x; 6.5969x over previous
//
#include <hip/hip_runtime.h>
#include <math.h>

#define BATCH   65536
#define DIM     64
#define HID     128
#define SPLIT   32
#define NBINS   8
#define PDIM    25          // 3*NBINS+1
#define NLAYERS 6
#define R_MIN   (-5.0f)
#define R_MAX   (5.0f)
#define MIN_BIN   1.0e-4f
#define MIN_SLOPE 1.0e-4f
#define SOFF      0.54116666f   // log(exp(1-MIN_SLOPE)-1)

#define ROWSW 16      // rows per wave
#define WAVES 4
#define MBLK  64      // rows per block
#define NT    256

#define N_W1  (HID*SPLIT)     // 4096
#define N_W2  (HID*HID)       // 16384
#define N_W4P (32*32*HID)     // 131072  (padded: 32 t-dims x 32 params x 128 k)
#define N_W4  (SPLIT*PDIM*HID) // 102400

typedef __attribute__((ext_vector_type(8))) short bf16x8;
typedef __attribute__((ext_vector_type(4))) float f32x4;

__device__ __forceinline__ short f2bf(float f) {
    unsigned u = __builtin_bit_cast(unsigned, f);
    unsigned r = u + 0x7FFFu + ((u >> 16) & 1u);   // RNE
    return (short)(r >> 16);
}

__device__ __forceinline__ bf16x8 cvt8(const float* src) {   // 8 consecutive f32 -> bf16x8
    float4 u = reinterpret_cast<const float4*>(src)[0];
    float4 v = reinterpret_cast<const float4*>(src)[1];
    bf16x8 a;
    a[0]=f2bf(u.x); a[1]=f2bf(u.y); a[2]=f2bf(u.z); a[3]=f2bf(u.w);
    a[4]=f2bf(v.x); a[5]=f2bf(v.y); a[6]=f2bf(v.z); a[7]=f2bf(v.w);
    return a;
}

// ---- weight conversion prologue: fp32 -> bf16 (W4 padded to 32 params/t) ----
__global__ void cvt_weights(const float* __restrict__ W1, const float* __restrict__ W2,
                            const float* __restrict__ W3, const float* __restrict__ W4,
                            short* __restrict__ o1, short* __restrict__ o2,
                            short* __restrict__ o3, short* __restrict__ o4) {
    const int stride = gridDim.x * blockDim.x;
    const int i0 = blockIdx.x * blockDim.x + threadIdx.x;
    for (int i = i0; i < NLAYERS*N_W1; i += stride) o1[i] = f2bf(W1[i]);
    for (int i = i0; i < NLAYERS*N_W2; i += stride) o2[i] = f2bf(W2[i]);
    for (int i = i0; i < NLAYERS*N_W2; i += stride) o3[i] = f2bf(W3[i]);
    for (int i = i0; i < NLAYERS*N_W4P; i += stride) {
        const int L = i >> 17, rem = i & (N_W4P - 1);
        const int t = rem >> 12, rem2 = rem & 4095;
        const int p = rem2 >> 7, k = rem2 & 127;
        o4[i] = (p < PDIM) ? f2bf(W4[(size_t)L*N_W4 + (size_t)(t*PDIM + p)*HID + k])
                           : (short)0;
    }
}

// One coupling layer. Each WAVE owns 16 rows end-to-end (no __syncthreads).
// In-place (xin==yout) is safe for layers >=1: a wave reads all its rows'
// inputs before writing, and only touches its own rows' transformed dims.
__global__ __launch_bounds__(NT) void flow_layer(
    const float* xin, float* yout, float* logdet, const int first,
    const short* __restrict__ bW1, const float* __restrict__ b1,
    const short* __restrict__ bW2, const float* __restrict__ b2,
    const short* __restrict__ bW3, const float* __restrict__ b3,
    const short* __restrict__ bW4, const float* __restrict__ b4,
    const int* __restrict__ mi, const int* __restrict__ ti)
{
    __shared__ float act[WAVES][ROWSW][132];      // activations (f32), padded stride
    __shared__ float xts[WAVES][ROWSW][36];       // spline inputs
    __shared__ float par[WAVES][ROWSW][4][33];    // param staging (4 t-dims per pass)

    const int tid = threadIdx.x;
    const int w   = tid >> 6;    // wave id
    const int l   = tid & 63;    // lane
    const int lr  = l & 15;      // row-in-wave / col-in-tile
    const int lg  = l >> 4;      // 0..3 (k-group / t-local)
    const int rbase = blockIdx.x * MBLK + w * ROWSW;

    // ---- gather xm -> act[:, 0:32], xt -> xts (wave-private) ----
    {
        const int kcol = l & 31;
        const int mc = mi[kcol], tc = ti[kcol];
        const int r0 = l >> 5;                    // 0 or 1
        #pragma unroll
        for (int it = 0; it < 8; ++it) {
            const int r = r0 + it * 2;
            const float* row = xin + (size_t)(rbase + r) * DIM;
            const float mv = row[mc];
            act[w][r][kcol] = mv;
            xts[w][r][kcol] = row[tc];
            if (first) yout[(size_t)(rbase + r) * DIM + mc] = mv;  // copy-through (L0 only)
        }
    }

    // ---- h1 = relu(xm @ W1^T + b1)   [K=32 -> 1 MFMA per n-tile] ----
    {
        bf16x8 a0 = cvt8(&act[w][lr][lg * 8]);
        f32x4 c[8];
        #pragma unroll
        for (int nt = 0; nt < 8; ++nt) { const float bv = b1[nt*16 + lr]; c[nt] = (f32x4){bv,bv,bv,bv}; }
        #pragma unroll
        for (int nt = 0; nt < 8; ++nt) {
            const bf16x8 bfr = *reinterpret_cast<const bf16x8*>(bW1 + (size_t)(nt*16 + lr)*SPLIT + lg*8);
            c[nt] = __builtin_amdgcn_mfma_f32_16x16x32_bf16(a0, bfr, c[nt], 0, 0, 0);
        }
        #pragma unroll
        for (int nt = 0; nt < 8; ++nt)
            #pragma unroll
            for (int j = 0; j < 4; ++j)
                act[w][lg*4 + j][nt*16 + lr] = fmaxf(c[nt][j], 0.0f);
    }

    // ---- h2 = relu(h1 @ W2^T + b2)   [K=128] ----
    {
        bf16x8 a[4];
        #pragma unroll
        for (int kt = 0; kt < 4; ++kt) a[kt] = cvt8(&act[w][lr][kt*32 + lg*8]);
        f32x4 c[8];
        #pragma unroll
        for (int nt = 0; nt < 8; ++nt) { const float bv = b2[nt*16 + lr]; c[nt] = (f32x4){bv,bv,bv,bv}; }
        #pragma unroll
        for (int kt = 0; kt < 4; ++kt)
            #pragma unroll
            for (int nt = 0; nt < 8; ++nt) {
                const bf16x8 bfr = *reinterpret_cast<const bf16x8*>(bW2 + (size_t)(nt*16 + lr)*HID + kt*32 + lg*8);
                c[nt] = __builtin_amdgcn_mfma_f32_16x16x32_bf16(a[kt], bfr, c[nt], 0, 0, 0);
            }
        #pragma unroll
        for (int nt = 0; nt < 8; ++nt)
            #pragma unroll
            for (int j = 0; j < 4; ++j)
                act[w][lg*4 + j][nt*16 + lr] = fmaxf(c[nt][j], 0.0f);
    }

    // ---- h3 = relu(h2 @ W3^T + b3)   [K=128] ----
    {
        bf16x8 a[4];
        #pragma unroll
        for (int kt = 0; kt < 4; ++kt) a[kt] = cvt8(&act[w][lr][kt*32 + lg*8]);
        f32x4 c[8];
        #pragma unroll
        for (int nt = 0; nt < 8; ++nt) { const float bv = b3[nt*16 + lr]; c[nt] = (f32x4){bv,bv,bv,bv}; }
        #pragma unroll
        for (int kt = 0; kt < 4; ++kt)
            #pragma unroll
            for (int nt = 0; nt < 8; ++nt) {
                const bf16x8 bfr = *reinterpret_cast<const bf16x8*>(bW3 + (size_t)(nt*16 + lr)*HID + kt*32 + lg*8);
                c[nt] = __builtin_amdgcn_mfma_f32_16x16x32_bf16(a[kt], bfr, c[nt], 0, 0, 0);
            }
        #pragma unroll
        for (int nt = 0; nt < 8; ++nt)
            #pragma unroll
            for (int j = 0; j < 4; ++j)
                act[w][lg*4 + j][nt*16 + lr] = fmaxf(c[nt][j], 0.0f);
    }

    // ---- params (W4, padded 32/t) + RQS spline; 4 t-dims per pass ----
    bf16x8 a4[4];
    #pragma unroll
    for (int kt = 0; kt < 4; ++kt) a4[kt] = cvt8(&act[w][lr][kt*32 + lg*8]);

    float ldacc = 0.0f;
    #pragma unroll 1
    for (int tb = 0; tb < 8; ++tb) {
        f32x4 c[4][2];
        #pragma unroll
        for (int tl = 0; tl < 4; ++tl)
            #pragma unroll
            for (int h = 0; h < 2; ++h) {
                const int pp = h*16 + lr;
                const int t  = tb*4 + tl;
                const float bv = (pp < PDIM) ? b4[t*PDIM + pp] : 0.0f;
                c[tl][h] = (f32x4){bv, bv, bv, bv};
            }
        #pragma unroll
        for (int kt = 0; kt < 4; ++kt)
            #pragma unroll
            for (int tl = 0; tl < 4; ++tl)
                #pragma unroll
                for (int h = 0; h < 2; ++h) {
                    const size_t off = (size_t)((tb*4 + tl)*32 + h*16 + lr) * HID + kt*32 + lg*8;
                    const bf16x8 bfr = *reinterpret_cast<const bf16x8*>(bW4 + off);
                    c[tl][h] = __builtin_amdgcn_mfma_f32_16x16x32_bf16(a4[kt], bfr, c[tl][h], 0, 0, 0);
                }
        // stage params to LDS (rows lg*4+j, cols h*16+lr)
        #pragma unroll
        for (int tl = 0; tl < 4; ++tl)
            #pragma unroll
            for (int h = 0; h < 2; ++h)
                #pragma unroll
                for (int j = 0; j < 4; ++j)
                    par[w][lg*4 + j][tl][h*16 + lr] = c[tl][h][j];

        // ---- spline for (row = lr, t = tb*4 + lg) ----
        const int t = tb*4 + lg;
        float p[PDIM];
        #pragma unroll
        for (int j = 0; j < PDIM; ++j) p[j] = par[w][lr][lg][j];

        float wd[NBINS], hg[NBINS], sl[NBINS + 1];
        {
            float mx = p[0];
            #pragma unroll
            for (int i = 1; i < NBINS; ++i) mx = fmaxf(mx, p[i]);
            float sum = 0.0f;
            #pragma unroll
            for (int i = 0; i < NBINS; ++i) { wd[i] = __expf(p[i] - mx); sum += wd[i]; }
            const float sc = ((R_MAX - R_MIN) - NBINS * MIN_BIN) / sum;
            #pragma unroll
            for (int i = 0; i < NBINS; ++i) wd[i] = wd[i] * sc + MIN_BIN;
        }
        {
            float mx = p[NBINS];
            #pragma unroll
            for (int i = 1; i < NBINS; ++i) mx = fmaxf(mx, p[NBINS + i]);
            float sum = 0.0f;
            #pragma unroll
            for (int i = 0; i < NBINS; ++i) { hg[i] = __expf(p[NBINS + i] - mx); sum += hg[i]; }
            const float sc = ((R_MAX - R_MIN) - NBINS * MIN_BIN) / sum;
            #pragma unroll
            for (int i = 0; i < NBINS; ++i) hg[i] = hg[i] * sc + MIN_BIN;
        }
        #pragma unroll
        for (int i = 0; i < NBINS + 1; ++i) {
            const float z  = p[2*NBINS + i] + SOFF;
            const float sp = (z > 15.0f) ? z : log1pf(__expf(z));
            sl[i] = sp + MIN_SLOPE;
        }
        float xp[NBINS + 1], yp[NBINS + 1];
        xp[0] = R_MIN; yp[0] = R_MIN;
        #pragma unroll
        for (int i = 0; i < NBINS; ++i) { xp[i+1] = xp[i] + wd[i]; yp[i+1] = yp[i] + hg[i]; }

        const float x = xts[w][lr][t];
        int b = 0;
        #pragma unroll
        for (int i = 1; i < NBINS; ++i) b += (xp[i] <= x) ? 1 : 0;

        float x_k = xp[0], x_k1 = xp[1], y_k = yp[0], y_k1 = yp[1], d_k = sl[0], d_k1 = sl[1];
        #pragma unroll
        for (int i = 1; i < NBINS; ++i) {
            if (b == i) { x_k = xp[i]; x_k1 = xp[i+1]; y_k = yp[i]; y_k1 = yp[i+1];
                          d_k = sl[i]; d_k1 = sl[i+1]; }
        }

        const float wdt  = x_k1 - x_k;
        const float hgt  = y_k1 - y_k;
        float xi = (x - x_k) / wdt;
        xi = fminf(fmaxf(xi, 0.0f), 1.0f);
        const float s    = hgt / wdt;
        const float xi1m = 1.0f - xi;
        const float q    = xi * xi1m;
        const float num  = s * xi * xi + d_k * q;
        const float den  = s + (d_k1 + d_k - 2.0f * s) * q;
        const float y_sp = y_k + hgt * num / den;
        const float deriv = s * s * (d_k1 * xi * xi + 2.0f * s * q + d_k * xi1m * xi1m) / (den * den);

        const bool below = x < R_MIN;
        const bool above = x > R_MAX;
        const float yv = below ? ((x - R_MIN) * sl[0]     + R_MIN)
                       : (above ? ((x - R_MAX) * sl[NBINS] + R_MAX) : y_sp);
        const float dv = below ? sl[0] : (above ? sl[NBINS] : deriv);
        ldacc += __logf(dv);

        yout[(size_t)(rbase + lr) * DIM + ti[t]] = yv;
    }

    // per-row logdet: reduce across the 4 lane-groups (fixed order)
    ldacc += __shfl_xor(ldacc, 16, 64);
    ldacc += __shfl_xor(ldacc, 32, 64);
    if (l < 16) {
        const int row = rbase + lr;
        if (first) logdet[row] = ldacc;
        else       logdet[row] += ldacc;
    }
}

extern "C" void kernel_launch(void* const* d_in, const int* in_sizes, int n_in,
                              void* d_out, int out_size, void* d_ws, size_t ws_size,
                              hipStream_t stream) {
    const float* x  = (const float*)d_in[0];
    const float* W1 = (const float*)d_in[1];
    const float* b1 = (const float*)d_in[2];
    const float* W2 = (const float*)d_in[3];
    const float* b2 = (const float*)d_in[4];
    const float* W3 = (const float*)d_in[5];
    const float* b3 = (const float*)d_in[6];
    const float* W4 = (const float*)d_in[7];
    const float* b4 = (const float*)d_in[8];
    const int*   mi = (const int*)d_in[9];
    const int*   ti = (const int*)d_in[10];

    float* y      = (float*)d_out;
    float* logdet = y + (size_t)BATCH * DIM;

    short* bW1 = (short*)d_ws;
    short* bW2 = bW1 + NLAYERS * N_W1;
    short* bW3 = bW2 + NLAYERS * N_W2;
    short* bW4 = bW3 + NLAYERS * N_W2;

    cvt_weights<<<512, 256, 0, stream>>>(W1, W2, W3, W4, bW1, bW2, bW3, bW4);

    dim3 grid(BATCH / MBLK), block(NT);
    for (int L = 0; L < NLAYERS; ++L) {
        flow_layer<<<grid, block, 0, stream>>>(
            (L == 0) ? x : y, y, logdet, (L == 0) ? 1 : 0,
            bW1 + (size_t)L * N_W1, b1 + L * HID,
            bW2 + (size_t)L * N_W2, b2 + L * HID,
            bW3 + (size_t)L * N_W2, b3 + L * HID,
            bW4 + (size_t)L * N_W4P, b4 + (size_t)L * SPLIT * PDIM,
            mi + L * SPLIT, ti + L * SPLIT);
    }
}

// Round 3
// 1014.104 us; speedup vs baseline: 6.9111x; 1.0476x over previous
//
#include <hip/hip_runtime.h>
#include <math.h>

#define BATCH   65536
#define DIM     64
#define HID     128
#define SPLIT   32
#define NBINS   8
#define PDIM    25          // 3*NBINS+1
#define NLAYERS 6
#define R_MIN   (-5.0f)
#define R_MAX   (5.0f)
#define MIN_BIN   1.0e-4f
#define MIN_SLOPE 1.0e-4f
#define SOFF      0.54116666f   // log(exp(1-MIN_SLOPE)-1)

#define ROWSW 16      // rows per wave
#define WAVES 4
#define MBLK  64      // rows per block
#define NT    256

#define N_W1  (HID*SPLIT)      // 4096
#define N_W2  (HID*HID)        // 16384
#define N_W4P (32*32*HID)      // 131072  (padded: 32 t-dims x 32 params x 128 k)
#define N_W4  (SPLIT*PDIM*HID) // 102400

typedef __attribute__((ext_vector_type(8))) short bf16x8;
typedef __attribute__((ext_vector_type(4))) float f32x4;

__device__ __forceinline__ short f2bf(float f) {
    unsigned u = __builtin_bit_cast(unsigned, f);
    unsigned r = u + 0x7FFFu + ((u >> 16) & 1u);   // RNE
    return (short)(r >> 16);
}

__device__ __forceinline__ bf16x8 cvt8(const float* src) {   // 8 consecutive f32 -> bf16x8
    float4 u = reinterpret_cast<const float4*>(src)[0];
    float4 v = reinterpret_cast<const float4*>(src)[1];
    bf16x8 a;
    a[0]=f2bf(u.x); a[1]=f2bf(u.y); a[2]=f2bf(u.z); a[3]=f2bf(u.w);
    a[4]=f2bf(v.x); a[5]=f2bf(v.y); a[6]=f2bf(v.z); a[7]=f2bf(v.w);
    return a;
}

// ---- weight conversion prologue: fp32 -> bf16 (W4 padded to 32 params/t) ----
__global__ void cvt_weights(const float* __restrict__ W1, const float* __restrict__ W2,
                            const float* __restrict__ W3, const float* __restrict__ W4,
                            short* __restrict__ o1, short* __restrict__ o2,
                            short* __restrict__ o3, short* __restrict__ o4) {
    const int stride = gridDim.x * blockDim.x;
    const int i0 = blockIdx.x * blockDim.x + threadIdx.x;
    for (int i = i0; i < NLAYERS*N_W1; i += stride) o1[i] = f2bf(W1[i]);
    for (int i = i0; i < NLAYERS*N_W2; i += stride) o2[i] = f2bf(W2[i]);
    for (int i = i0; i < NLAYERS*N_W2; i += stride) o3[i] = f2bf(W3[i]);
    for (int i = i0; i < NLAYERS*N_W4P; i += stride) {
        const int L = i >> 17, rem = i & (N_W4P - 1);
        const int t = rem >> 12, rem2 = rem & 4095;
        const int p = rem2 >> 7, k = rem2 & 127;
        o4[i] = (p < PDIM) ? f2bf(W4[(size_t)L*N_W4 + (size_t)(t*PDIM + p)*HID + k])
                           : (short)0;
    }
}

// One coupling layer. Each WAVE owns 16 rows end-to-end (no __syncthreads).
// act (activations) and par (param staging) OVERLAY the same LDS pool:
// act is dead once the a4 fragments are in registers, and DS ops from the
// same wave are ordered, so the per-wave overlay needs no barrier.
__global__ __launch_bounds__(NT, 2) void flow_layer(
    const float* xin, float* yout, float* logdet, const int first,
    const short* __restrict__ bW1, const float* __restrict__ b1,
    const short* __restrict__ bW2, const float* __restrict__ b2,
    const short* __restrict__ bW3, const float* __restrict__ b3,
    const short* __restrict__ bW4, const float* __restrict__ b4,
    const int* __restrict__ mi, const int* __restrict__ ti)
{
    // pool(w, r, k) row stride 132 floats; par view: (w, r, tl, c) = tl*33 + c
    __shared__ alignas(16) float pool[WAVES * ROWSW * 132];
    __shared__ float xts[WAVES][ROWSW][36];       // spline inputs

    const int tid = threadIdx.x;
    const int w   = tid >> 6;    // wave id
    const int l   = tid & 63;    // lane
    const int lr  = l & 15;      // row-in-wave / col-in-tile
    const int lg  = l >> 4;      // 0..3 (k-group / t-local)
    const int rbase = blockIdx.x * MBLK + w * ROWSW;

    float* const actw = &pool[(w * ROWSW) * 132];   // wave-private region

    // ---- gather xm -> act[:, 0:32], xt -> xts (wave-private) ----
    {
        const int kcol = l & 31;
        const int mc = mi[kcol], tc = ti[kcol];
        const int r0 = l >> 5;                    // 0 or 1
        #pragma unroll
        for (int it = 0; it < 8; ++it) {
            const int r = r0 + it * 2;
            const float* row = xin + (size_t)(rbase + r) * DIM;
            const float mv = row[mc];
            actw[r * 132 + kcol] = mv;
            xts[w][r][kcol] = row[tc];
            if (first) yout[(size_t)(rbase + r) * DIM + mc] = mv;  // copy-through (L0 only)
        }
    }

    // ---- h1 = relu(xm @ W1^T + b1)   [K=32] ----
    {
        bf16x8 a0 = cvt8(&actw[lr * 132 + lg * 8]);
        f32x4 c[8];
        #pragma unroll
        for (int nt = 0; nt < 8; ++nt) { const float bv = b1[nt*16 + lr]; c[nt] = (f32x4){bv,bv,bv,bv}; }
        #pragma unroll
        for (int nt = 0; nt < 8; ++nt) {
            const bf16x8 bfr = *reinterpret_cast<const bf16x8*>(bW1 + (size_t)(nt*16 + lr)*SPLIT + lg*8);
            c[nt] = __builtin_amdgcn_mfma_f32_16x16x32_bf16(a0, bfr, c[nt], 0, 0, 0);
        }
        #pragma unroll
        for (int nt = 0; nt < 8; ++nt)
            #pragma unroll
            for (int j = 0; j < 4; ++j)
                actw[(lg*4 + j) * 132 + nt*16 + lr] = fmaxf(c[nt][j], 0.0f);
    }

    // ---- h2 = relu(h1 @ W2^T + b2)   [K=128] ----
    {
        bf16x8 a[4];
        #pragma unroll
        for (int kt = 0; kt < 4; ++kt) a[kt] = cvt8(&actw[lr * 132 + kt*32 + lg*8]);
        f32x4 c[8];
        #pragma unroll
        for (int nt = 0; nt < 8; ++nt) { const float bv = b2[nt*16 + lr]; c[nt] = (f32x4){bv,bv,bv,bv}; }
        #pragma unroll
        for (int kt = 0; kt < 4; ++kt)
            #pragma unroll
            for (int nt = 0; nt < 8; ++nt) {
                const bf16x8 bfr = *reinterpret_cast<const bf16x8*>(bW2 + (size_t)(nt*16 + lr)*HID + kt*32 + lg*8);
                c[nt] = __builtin_amdgcn_mfma_f32_16x16x32_bf16(a[kt], bfr, c[nt], 0, 0, 0);
            }
        #pragma unroll
        for (int nt = 0; nt < 8; ++nt)
            #pragma unroll
            for (int j = 0; j < 4; ++j)
                actw[(lg*4 + j) * 132 + nt*16 + lr] = fmaxf(c[nt][j], 0.0f);
    }

    // ---- h3 = relu(h2 @ W3^T + b3)   [K=128] ----
    {
        bf16x8 a[4];
        #pragma unroll
        for (int kt = 0; kt < 4; ++kt) a[kt] = cvt8(&actw[lr * 132 + kt*32 + lg*8]);
        f32x4 c[8];
        #pragma unroll
        for (int nt = 0; nt < 8; ++nt) { const float bv = b3[nt*16 + lr]; c[nt] = (f32x4){bv,bv,bv,bv}; }
        #pragma unroll
        for (int kt = 0; kt < 4; ++kt)
            #pragma unroll
            for (int nt = 0; nt < 8; ++nt) {
                const bf16x8 bfr = *reinterpret_cast<const bf16x8*>(bW3 + (size_t)(nt*16 + lr)*HID + kt*32 + lg*8);
                c[nt] = __builtin_amdgcn_mfma_f32_16x16x32_bf16(a[kt], bfr, c[nt], 0, 0, 0);
            }
        #pragma unroll
        for (int nt = 0; nt < 8; ++nt)
            #pragma unroll
            for (int j = 0; j < 4; ++j)
                actw[(lg*4 + j) * 132 + nt*16 + lr] = fmaxf(c[nt][j], 0.0f);
    }

    // ---- a4 fragments into registers; act region is DEAD after this ----
    bf16x8 a4[4];
    #pragma unroll
    for (int kt = 0; kt < 4; ++kt) a4[kt] = cvt8(&actw[lr * 132 + kt*32 + lg*8]);

    // ---- params (W4, padded 32/t) + RQS spline; 4 t-dims per pass ----
    float ldacc = 0.0f;
    #pragma unroll 1
    for (int tb = 0; tb < 8; ++tb) {
        f32x4 c[4][2];
        #pragma unroll
        for (int tl = 0; tl < 4; ++tl)
            #pragma unroll
            for (int h = 0; h < 2; ++h) {
                const int pp = h*16 + lr;
                const int t  = tb*4 + tl;
                const float bv = (pp < PDIM) ? b4[t*PDIM + pp] : 0.0f;
                c[tl][h] = (f32x4){bv, bv, bv, bv};
            }
        #pragma unroll
        for (int kt = 0; kt < 4; ++kt)
            #pragma unroll
            for (int tl = 0; tl < 4; ++tl)
                #pragma unroll
                for (int h = 0; h < 2; ++h) {
                    const size_t off = (size_t)((tb*4 + tl)*32 + h*16 + lr) * HID + kt*32 + lg*8;
                    const bf16x8 bfr = *reinterpret_cast<const bf16x8*>(bW4 + off);
                    c[tl][h] = __builtin_amdgcn_mfma_f32_16x16x32_bf16(a4[kt], bfr, c[tl][h], 0, 0, 0);
                }
        // stage params to LDS overlay (row lg*4+j, slot tl, col h*16+lr)
        #pragma unroll
        for (int tl = 0; tl < 4; ++tl)
            #pragma unroll
            for (int h = 0; h < 2; ++h)
                #pragma unroll
                for (int j = 0; j < 4; ++j)
                    actw[(lg*4 + j) * 132 + tl*33 + h*16 + lr] = c[tl][h][j];

        // ---- spline for (row = lr, t = tb*4 + lg), staged LDS reads ----
        const float* prow = &actw[lr * 132 + lg * 33];

        float sl[NBINS + 1];
        #pragma unroll
        for (int i = 0; i < NBINS + 1; ++i) {
            const float z = prow[2*NBINS + i] + SOFF;
            const float sp = (z > 15.0f) ? z : __logf(1.0f + __expf(z));
            sl[i] = sp + MIN_SLOPE;
        }

        float wd[NBINS];
        {
            float q[NBINS];
            #pragma unroll
            for (int i = 0; i < NBINS; ++i) q[i] = prow[i];
            float mx = q[0];
            #pragma unroll
            for (int i = 1; i < NBINS; ++i) mx = fmaxf(mx, q[i]);
            float sum = 0.0f;
            #pragma unroll
            for (int i = 0; i < NBINS; ++i) { wd[i] = __expf(q[i] - mx); sum += wd[i]; }
            const float sc = __fdividef((R_MAX - R_MIN) - NBINS * MIN_BIN, sum);
            #pragma unroll
            for (int i = 0; i < NBINS; ++i) wd[i] = wd[i] * sc + MIN_BIN;
        }
        float hg[NBINS];
        {
            float q[NBINS];
            #pragma unroll
            for (int i = 0; i < NBINS; ++i) q[i] = prow[NBINS + i];
            float mx = q[0];
            #pragma unroll
            for (int i = 1; i < NBINS; ++i) mx = fmaxf(mx, q[i]);
            float sum = 0.0f;
            #pragma unroll
            for (int i = 0; i < NBINS; ++i) { hg[i] = __expf(q[i] - mx); sum += hg[i]; }
            const float sc = __fdividef((R_MAX - R_MIN) - NBINS * MIN_BIN, sum);
            #pragma unroll
            for (int i = 0; i < NBINS; ++i) hg[i] = hg[i] * sc + MIN_BIN;
        }

        const float x = xts[w][lr][tb*4 + lg];

        // bin search on running cumsum (x_pos[i] = R_MIN + sum_{j<i} wd[j])
        int b = 0;
        {
            float cx = R_MIN;
            #pragma unroll
            for (int i = 1; i < NBINS; ++i) { cx += wd[i-1]; b += (cx <= x) ? 1 : 0; }
        }
        // select knot values at i==b with running sums (no xp/yp arrays)
        float x_k = R_MIN, y_k = R_MIN, wsel = wd[0], hsel = hg[0], d_k = sl[0], d_k1 = sl[1];
        {
            float cx = R_MIN, cy = R_MIN;
            #pragma unroll
            for (int i = 0; i < NBINS; ++i) {
                if (i == b) { x_k = cx; y_k = cy; wsel = wd[i]; hsel = hg[i];
                              d_k = sl[i]; d_k1 = sl[i+1]; }
                cx += wd[i]; cy += hg[i];
            }
        }

        const float invw = __fdividef(1.0f, wsel);
        float xi = (x - x_k) * invw;
        xi = fminf(fmaxf(xi, 0.0f), 1.0f);
        const float s    = hsel * invw;
        const float xi1m = 1.0f - xi;
        const float q    = xi * xi1m;
        const float num  = s * xi * xi + d_k * q;
        const float den  = s + (d_k1 + d_k - 2.0f * s) * q;
        const float invden = __fdividef(1.0f, den);
        const float y_sp = y_k + hsel * num * invden;
        const float deriv = s * s * (d_k1 * xi * xi + 2.0f * s * q + d_k * xi1m * xi1m)
                            * invden * invden;

        const bool below = x < R_MIN;
        const bool above = x > R_MAX;
        const float yv = below ? ((x - R_MIN) * sl[0]     + R_MIN)
                       : (above ? ((x - R_MAX) * sl[NBINS] + R_MAX) : y_sp);
        const float dv = below ? sl[0] : (above ? sl[NBINS] : deriv);
        ldacc += __logf(dv);

        yout[(size_t)(rbase + lr) * DIM + ti[tb*4 + lg]] = yv;
    }

    // per-row logdet: reduce across the 4 lane-groups (fixed order)
    ldacc += __shfl_xor(ldacc, 16, 64);
    ldacc += __shfl_xor(ldacc, 32, 64);
    if (l < 16) {
        const int row = rbase + lr;
        if (first) logdet[row] = ldacc;
        else       logdet[row] += ldacc;
    }
}

extern "C" void kernel_launch(void* const* d_in, const int* in_sizes, int n_in,
                              void* d_out, int out_size, void* d_ws, size_t ws_size,
                              hipStream_t stream) {
    const float* x  = (const float*)d_in[0];
    const float* W1 = (const float*)d_in[1];
    const float* b1 = (const float*)d_in[2];
    const float* W2 = (const float*)d_in[3];
    const float* b2 = (const float*)d_in[4];
    const float* W3 = (const float*)d_in[5];
    const float* b3 = (const float*)d_in[6];
    const float* W4 = (const float*)d_in[7];
    const float* b4 = (const float*)d_in[8];
    const int*   mi = (const int*)d_in[9];
    const int*   ti = (const int*)d_in[10];

    float* y      = (float*)d_out;
    float* logdet = y + (size_t)BATCH * DIM;

    short* bW1 = (short*)d_ws;
    short* bW2 = bW1 + NLAYERS * N_W1;
    short* bW3 = bW2 + NLAYERS * N_W2;
    short* bW4 = bW3 + NLAYERS * N_W2;

    cvt_weights<<<512, 256, 0, stream>>>(W1, W2, W3, W4, bW1, bW2, bW3, bW4);

    dim3 grid(BATCH / MBLK), block(NT);
    for (int L = 0; L < NLAYERS; ++L) {
        flow_layer<<<grid, block, 0, stream>>>(
            (L == 0) ? x : y, y, logdet, (L == 0) ? 1 : 0,
            bW1 + (size_t)L * N_W1, b1 + L * HID,
            bW2 + (size_t)L * N_W2, b2 + L * HID,
            bW3 + (size_t)L * N_W2, b3 + L * HID,
            bW4 + (size_t)L * N_W4P, b4 + (size_t)L * SPLIT * PDIM,
            mi + L * SPLIT, ti + L * SPLIT);
    }
}

// Round 4
// 384.507 us; speedup vs baseline: 18.2274x; 2.6374x over previous
//
#include <hip/hip_runtime.h>
#include <math.h>

#define BATCH   65536
#define DIM     64
#define HID     128
#define SPLIT   32
#define NBINS   8
#define PDIM    25          // 3*NBINS+1
#define NLAYERS 6
#define R_MIN   (-5.0f)
#define R_MAX   (5.0f)
#define MIN_BIN   1.0e-4f
#define MIN_SLOPE 1.0e-4f
#define SOFF      0.54116666f   // log(exp(1-MIN_SLOPE)-1)

#define ROWSW 16      // rows per wave
#define WAVES 4
#define MBLK  64      // rows per block
#define NT    256

#define N_W1  (HID*SPLIT)      // 4096
#define N_W2  (HID*HID)        // 16384
#define N_W4P (32*32*HID)      // 131072  (padded: 32 t-dims x 32 params x 128 k)
#define N_W4  (SPLIT*PDIM*HID) // 102400

typedef __attribute__((ext_vector_type(8))) short bf16x8;
typedef __attribute__((ext_vector_type(4))) float f32x4;

__device__ __forceinline__ short f2bf(float f) {
    unsigned u = __builtin_bit_cast(unsigned, f);
    unsigned r = u + 0x7FFFu + ((u >> 16) & 1u);   // RNE
    return (short)(r >> 16);
}

__device__ __forceinline__ bf16x8 cvt8(const float* src) {   // 8 consecutive f32 -> bf16x8
    float4 u = reinterpret_cast<const float4*>(src)[0];
    float4 v = reinterpret_cast<const float4*>(src)[1];
    bf16x8 a;
    a[0]=f2bf(u.x); a[1]=f2bf(u.y); a[2]=f2bf(u.z); a[3]=f2bf(u.w);
    a[4]=f2bf(v.x); a[5]=f2bf(v.y); a[6]=f2bf(v.z); a[7]=f2bf(v.w);
    return a;
}

// ---- weight conversion prologue: fp32 -> bf16, repacked in MFMA FRAGMENT
// ORDER: each 16(n) x 32(k) B-tile is a 1KB chunk of 64 lanes x 16B, so the
// kernel loads `chunk_base + lane*16B` (fully coalesced, 8 cache lines).
// Lane l holds B[row = l&15][k = (l>>4)*8 .. +8). W4 padded to 32 params/t.
__global__ void cvt_weights(const float* __restrict__ W1, const float* __restrict__ W2,
                            const float* __restrict__ W3, const float* __restrict__ W4,
                            short* __restrict__ o1, short* __restrict__ o2,
                            short* __restrict__ o3, short* __restrict__ o4) {
    const int stride = gridDim.x * blockDim.x;
    const int i0 = blockIdx.x * blockDim.x + threadIdx.x;
    // W1: chunks nt=0..7 (k-tile single)
    for (int i = i0; i < NLAYERS*N_W1; i += stride) {
        const int L = i >> 12, rem = i & 4095;
        const int nt = rem >> 9, q = rem & 511;
        const int l = q >> 3, e = q & 7;
        o1[i] = f2bf(W1[L*N_W1 + (nt*16 + (l&15))*SPLIT + (l>>4)*8 + e]);
    }
    // W2/W3: chunks c = nt*4 + kt
    for (int i = i0; i < NLAYERS*N_W2; i += stride) {
        const int L = i >> 14, rem = i & 16383;
        const int c = rem >> 9, q = rem & 511;
        const int nt = c >> 2, kt = c & 3;
        const int l = q >> 3, e = q & 7;
        const int src = L*N_W2 + (nt*16 + (l&15))*HID + kt*32 + (l>>4)*8 + e;
        o2[i] = f2bf(W2[src]);
        o3[i] = f2bf(W3[src]);
    }
    // W4: chunks c = t*8 + h*4 + kt   (t = 0..31, h = param-half, kt = k-tile)
    for (int i = i0; i < NLAYERS*N_W4P; i += stride) {
        const int L = i >> 17, rem = i & (N_W4P - 1);
        const int c = rem >> 9, q = rem & 511;
        const int t = c >> 3, h = (c >> 2) & 1, kt = c & 3;
        const int l = q >> 3, e = q & 7;
        const int pp = h*16 + (l & 15);
        o4[i] = (pp < PDIM)
              ? f2bf(W4[(size_t)L*N_W4 + (size_t)(t*PDIM + pp)*HID + kt*32 + (l>>4)*8 + e])
              : (short)0;
    }
}

// One coupling layer. Each WAVE owns 16 rows end-to-end (no __syncthreads).
__global__ __launch_bounds__(NT, 2) void flow_layer(
    const float* xin, float* yout, float* logdet, const int first,
    const short* __restrict__ bW1, const float* __restrict__ b1,
    const short* __restrict__ bW2, const float* __restrict__ b2,
    const short* __restrict__ bW3, const float* __restrict__ b3,
    const short* __restrict__ bW4, const float* __restrict__ b4,
    const int* __restrict__ mi, const int* __restrict__ ti)
{
    // pool(w, r, k) row stride 132 floats; par view: (w, r, tl, c) = tl*33 + c
    __shared__ alignas(16) float pool[WAVES * ROWSW * 132];
    __shared__ float xts[WAVES][ROWSW][36];       // spline inputs

    const int tid = threadIdx.x;
    const int w   = tid >> 6;    // wave id
    const int l   = tid & 63;    // lane
    const int lr  = l & 15;      // row-in-wave / col-in-tile
    const int lg  = l >> 4;      // 0..3 (k-group / t-local)
    const int rbase = blockIdx.x * MBLK + w * ROWSW;

    float* const actw = &pool[(w * ROWSW) * 132];   // wave-private region

    // ---- gather xm -> act[:, 0:32], xt -> xts (wave-private) ----
    {
        const int kcol = l & 31;
        const int mc = mi[kcol], tc = ti[kcol];
        const int r0 = l >> 5;                    // 0 or 1
        #pragma unroll
        for (int it = 0; it < 8; ++it) {
            const int r = r0 + it * 2;
            const float* row = xin + (size_t)(rbase + r) * DIM;
            const float mv = row[mc];
            actw[r * 132 + kcol] = mv;
            xts[w][r][kcol] = row[tc];
            if (first) yout[(size_t)(rbase + r) * DIM + mc] = mv;  // copy-through (L0 only)
        }
    }

    // ---- h1 = relu(xm @ W1^T + b1)   [K=32] ----
    {
        bf16x8 a0 = cvt8(&actw[lr * 132 + lg * 8]);
        f32x4 c[8];
        #pragma unroll
        for (int nt = 0; nt < 8; ++nt) { const float bv = b1[nt*16 + lr]; c[nt] = (f32x4){bv,bv,bv,bv}; }
        #pragma unroll
        for (int nt = 0; nt < 8; ++nt) {
            const bf16x8 bfr = *reinterpret_cast<const bf16x8*>(bW1 + (size_t)nt*512 + l*8);
            c[nt] = __builtin_amdgcn_mfma_f32_16x16x32_bf16(a0, bfr, c[nt], 0, 0, 0);
        }
        #pragma unroll
        for (int nt = 0; nt < 8; ++nt)
            #pragma unroll
            for (int j = 0; j < 4; ++j)
                actw[(lg*4 + j) * 132 + nt*16 + lr] = fmaxf(c[nt][j], 0.0f);
    }

    // ---- h2 = relu(h1 @ W2^T + b2)   [K=128] ----
    {
        bf16x8 a[4];
        #pragma unroll
        for (int kt = 0; kt < 4; ++kt) a[kt] = cvt8(&actw[lr * 132 + kt*32 + lg*8]);
        f32x4 c[8];
        #pragma unroll
        for (int nt = 0; nt < 8; ++nt) { const float bv = b2[nt*16 + lr]; c[nt] = (f32x4){bv,bv,bv,bv}; }
        #pragma unroll
        for (int kt = 0; kt < 4; ++kt)
            #pragma unroll
            for (int nt = 0; nt < 8; ++nt) {
                const bf16x8 bfr = *reinterpret_cast<const bf16x8*>(bW2 + (size_t)(nt*4 + kt)*512 + l*8);
                c[nt] = __builtin_amdgcn_mfma_f32_16x16x32_bf16(a[kt], bfr, c[nt], 0, 0, 0);
            }
        #pragma unroll
        for (int nt = 0; nt < 8; ++nt)
            #pragma unroll
            for (int j = 0; j < 4; ++j)
                actw[(lg*4 + j) * 132 + nt*16 + lr] = fmaxf(c[nt][j], 0.0f);
    }

    // ---- h3 = relu(h2 @ W3^T + b3)   [K=128] ----
    {
        bf16x8 a[4];
        #pragma unroll
        for (int kt = 0; kt < 4; ++kt) a[kt] = cvt8(&actw[lr * 132 + kt*32 + lg*8]);
        f32x4 c[8];
        #pragma unroll
        for (int nt = 0; nt < 8; ++nt) { const float bv = b3[nt*16 + lr]; c[nt] = (f32x4){bv,bv,bv,bv}; }
        #pragma unroll
        for (int kt = 0; kt < 4; ++kt)
            #pragma unroll
            for (int nt = 0; nt < 8; ++nt) {
                const bf16x8 bfr = *reinterpret_cast<const bf16x8*>(bW3 + (size_t)(nt*4 + kt)*512 + l*8);
                c[nt] = __builtin_amdgcn_mfma_f32_16x16x32_bf16(a[kt], bfr, c[nt], 0, 0, 0);
            }
        #pragma unroll
        for (int nt = 0; nt < 8; ++nt)
            #pragma unroll
            for (int j = 0; j < 4; ++j)
                actw[(lg*4 + j) * 132 + nt*16 + lr] = fmaxf(c[nt][j], 0.0f);
    }

    // ---- a4 fragments into registers; act region is DEAD after this ----
    bf16x8 a4[4];
    #pragma unroll
    for (int kt = 0; kt < 4; ++kt) a4[kt] = cvt8(&actw[lr * 132 + kt*32 + lg*8]);

    // ---- params (W4, padded 32/t) + RQS spline; 4 t-dims per pass ----
    float ldacc = 0.0f;
    #pragma unroll 1
    for (int tb = 0; tb < 8; ++tb) {
        f32x4 c[4][2];
        #pragma unroll
        for (int tl = 0; tl < 4; ++tl)
            #pragma unroll
            for (int h = 0; h < 2; ++h) {
                const int pp = h*16 + lr;
                const int t  = tb*4 + tl;
                const float bv = (pp < PDIM) ? b4[t*PDIM + pp] : 0.0f;
                c[tl][h] = (f32x4){bv, bv, bv, bv};
            }
        #pragma unroll
        for (int kt = 0; kt < 4; ++kt)
            #pragma unroll
            for (int tl = 0; tl < 4; ++tl)
                #pragma unroll
                for (int h = 0; h < 2; ++h) {
                    const bf16x8 bfr = *reinterpret_cast<const bf16x8*>(
                        bW4 + (size_t)((tb*4 + tl)*8 + h*4 + kt)*512 + l*8);
                    c[tl][h] = __builtin_amdgcn_mfma_f32_16x16x32_bf16(a4[kt], bfr, c[tl][h], 0, 0, 0);
                }
        // stage params to LDS overlay (row lg*4+j, slot tl, col h*16+lr)
        #pragma unroll
        for (int tl = 0; tl < 4; ++tl)
            #pragma unroll
            for (int h = 0; h < 2; ++h)
                #pragma unroll
                for (int j = 0; j < 4; ++j)
                    actw[(lg*4 + j) * 132 + tl*33 + h*16 + lr] = c[tl][h][j];

        // ---- spline for (row = lr, t = tb*4 + lg), staged LDS reads ----
        const float* prow = &actw[lr * 132 + lg * 33];

        float sl[NBINS + 1];
        #pragma unroll
        for (int i = 0; i < NBINS + 1; ++i) {
            const float z = prow[2*NBINS + i] + SOFF;
            const float sp = (z > 15.0f) ? z : __logf(1.0f + __expf(z));
            sl[i] = sp + MIN_SLOPE;
        }

        float wd[NBINS];
        {
            float q[NBINS];
            #pragma unroll
            for (int i = 0; i < NBINS; ++i) q[i] = prow[i];
            float mx = q[0];
            #pragma unroll
            for (int i = 1; i < NBINS; ++i) mx = fmaxf(mx, q[i]);
            float sum = 0.0f;
            #pragma unroll
            for (int i = 0; i < NBINS; ++i) { wd[i] = __expf(q[i] - mx); sum += wd[i]; }
            const float sc = __fdividef((R_MAX - R_MIN) - NBINS * MIN_BIN, sum);
            #pragma unroll
            for (int i = 0; i < NBINS; ++i) wd[i] = wd[i] * sc + MIN_BIN;
        }
        float hg[NBINS];
        {
            float q[NBINS];
            #pragma unroll
            for (int i = 0; i < NBINS; ++i) q[i] = prow[NBINS + i];
            float mx = q[0];
            #pragma unroll
            for (int i = 1; i < NBINS; ++i) mx = fmaxf(mx, q[i]);
            float sum = 0.0f;
            #pragma unroll
            for (int i = 0; i < NBINS; ++i) { hg[i] = __expf(q[i] - mx); sum += hg[i]; }
            const float sc = __fdividef((R_MAX - R_MIN) - NBINS * MIN_BIN, sum);
            #pragma unroll
            for (int i = 0; i < NBINS; ++i) hg[i] = hg[i] * sc + MIN_BIN;
        }

        const float x = xts[w][lr][tb*4 + lg];

        // bin search on running cumsum (x_pos[i] = R_MIN + sum_{j<i} wd[j])
        int b = 0;
        {
            float cx = R_MIN;
            #pragma unroll
            for (int i = 1; i < NBINS; ++i) { cx += wd[i-1]; b += (cx <= x) ? 1 : 0; }
        }
        // select knot values at i==b with running sums (no xp/yp arrays)
        float x_k = R_MIN, y_k = R_MIN, wsel = wd[0], hsel = hg[0], d_k = sl[0], d_k1 = sl[1];
        {
            float cx = R_MIN, cy = R_MIN;
            #pragma unroll
            for (int i = 0; i < NBINS; ++i) {
                if (i == b) { x_k = cx; y_k = cy; wsel = wd[i]; hsel = hg[i];
                              d_k = sl[i]; d_k1 = sl[i+1]; }
                cx += wd[i]; cy += hg[i];
            }
        }

        const float invw = __fdividef(1.0f, wsel);
        float xi = (x - x_k) * invw;
        xi = fminf(fmaxf(xi, 0.0f), 1.0f);
        const float s    = hsel * invw;
        const float xi1m = 1.0f - xi;
        const float q    = xi * xi1m;
        const float num  = s * xi * xi + d_k * q;
        const float den  = s + (d_k1 + d_k - 2.0f * s) * q;
        const float invden = __fdividef(1.0f, den);
        const float y_sp = y_k + hsel * num * invden;
        const float deriv = s * s * (d_k1 * xi * xi + 2.0f * s * q + d_k * xi1m * xi1m)
                            * invden * invden;

        const bool below = x < R_MIN;
        const bool above = x > R_MAX;
        const float yv = below ? ((x - R_MIN) * sl[0]     + R_MIN)
                       : (above ? ((x - R_MAX) * sl[NBINS] + R_MAX) : y_sp);
        const float dv = below ? sl[0] : (above ? sl[NBINS] : deriv);
        ldacc += __logf(dv);

        yout[(size_t)(rbase + lr) * DIM + ti[tb*4 + lg]] = yv;
    }

    // per-row logdet: reduce across the 4 lane-groups (fixed order)
    ldacc += __shfl_xor(ldacc, 16, 64);
    ldacc += __shfl_xor(ldacc, 32, 64);
    if (l < 16) {
        const int row = rbase + lr;
        if (first) logdet[row] = ldacc;
        else       logdet[row] += ldacc;
    }
}

extern "C" void kernel_launch(void* const* d_in, const int* in_sizes, int n_in,
                              void* d_out, int out_size, void* d_ws, size_t ws_size,
                              hipStream_t stream) {
    const float* x  = (const float*)d_in[0];
    const float* W1 = (const float*)d_in[1];
    const float* b1 = (const float*)d_in[2];
    const float* W2 = (const float*)d_in[3];
    const float* b2 = (const float*)d_in[4];
    const float* W3 = (const float*)d_in[5];
    const float* b3 = (const float*)d_in[6];
    const float* W4 = (const float*)d_in[7];
    const float* b4 = (const float*)d_in[8];
    const int*   mi = (const int*)d_in[9];
    const int*   ti = (const int*)d_in[10];

    float* y      = (float*)d_out;
    float* logdet = y + (size_t)BATCH * DIM;

    short* bW1 = (short*)d_ws;
    short* bW2 = bW1 + NLAYERS * N_W1;
    short* bW3 = bW2 + NLAYERS * N_W2;
    short* bW4 = bW3 + NLAYERS * N_W2;

    cvt_weights<<<512, 256, 0, stream>>>(W1, W2, W3, W4, bW1, bW2, bW3, bW4);

    dim3 grid(BATCH / MBLK), block(NT);
    for (int L = 0; L < NLAYERS; ++L) {
        flow_layer<<<grid, block, 0, stream>>>(
            (L == 0) ? x : y, y, logdet, (L == 0) ? 1 : 0,
            bW1 + (size_t)L * N_W1, b1 + L * HID,
            bW2 + (size_t)L * N_W2, b2 + L * HID,
            bW3 + (size_t)L * N_W2, b3 + L * HID,
            bW4 + (size_t)L * N_W4P, b4 + (size_t)L * SPLIT * PDIM,
            mi + L * SPLIT, ti + L * SPLIT);
    }
}